// Round 1
// baseline (2505.913 us; speedup 1.0000x reference)
//
#include <hip/hip_runtime.h>
#include <math.h>

#define BATCH 4
#define SEQ   2048
#define TOK   (BATCH * SEQ)   // 8192
#define DM    1024
#define DP    1024
#define NH    16
#define DH    64
#define NLAB  8
#define QKV_C 3072

// ---------------- kernel 1: bucket tokens by label ----------------
__global__ void build_lists_k(const int* __restrict__ L, int* __restrict__ sorted,
                              int* __restrict__ desc, int* __restrict__ numt) {
  __shared__ int cnt[NLAB], off[NLAB], cur[NLAB];
  int tid = threadIdx.x;
  if (tid < NLAB) cnt[tid] = 0;
  __syncthreads();
  for (int i = tid; i < TOK; i += blockDim.x) atomicAdd(&cnt[L[i]], 1);
  __syncthreads();
  if (tid == 0) {
    int o = 0;
    for (int l = 0; l < NLAB; ++l) { off[l] = o; cur[l] = o; o += cnt[l]; }
  }
  __syncthreads();
  for (int i = tid; i < TOK; i += blockDim.x) {
    int l = L[i];
    int p = atomicAdd(&cur[l], 1);
    sorted[p] = i;
  }
  if (tid == 0) {
    int nt = 0;
    for (int l = 0; l < NLAB; ++l) {
      int c = cnt[l], o = off[l];
      for (int t = 0; t < c; t += 32) {
        int rows = c - t; if (rows > 32) rows = 32;
        desc[nt++] = (o + t) | (l << 16) | (rows << 20);
      }
    }
    *numt = nt;
  }
}

// ---------------- kernel 2: label-routed QKV GEMM ----------------
// tile: TM=32 tokens x TN=256 out-cols, BK=32; 256 threads, 4x8 micro-tile
#define TM 32
#define TN 256
#define BK 32

__global__ __launch_bounds__(256) void qkv_gemm_k(
    const float* __restrict__ X, const float* __restrict__ Wqkv,
    const float* __restrict__ bqkv, const int* __restrict__ sorted,
    const int* __restrict__ desc, const int* __restrict__ numt,
    float* __restrict__ qkv) {
  int tile = blockIdx.y;
  if (tile >= *numt) return;
  int dsc   = desc[tile];
  int start = dsc & 0xFFFF;
  int lab   = (dsc >> 16) & 7;
  int rows  = (dsc >> 20) & 63;
  int c0    = blockIdx.x * TN;
  const float* W = Wqkv + (size_t)lab * DM * QKV_C;

  __shared__ float XsT[BK][TM + 4];   // [k][m], transposed for b128 reads
  __shared__ float Ws[BK][TN];

  int tid = threadIdx.x;
  int tx = tid & 31;   // col group: cols tx*8 .. tx*8+7
  int ty = tid >> 5;   // row group: rows ty*4 .. ty*4+3

  int lrow = tid >> 3;           // X-load: row 0..31
  int lk4  = (tid & 7) << 2;     // X-load: k offset 0..28
  int ltok = (lrow < rows) ? sorted[start + lrow] : -1;

  float acc[4][8];
  #pragma unroll
  for (int i = 0; i < 4; ++i)
    #pragma unroll
    for (int j = 0; j < 8; ++j) acc[i][j] = 0.f;

  for (int k0 = 0; k0 < DM; k0 += BK) {
    float4 xv = make_float4(0.f, 0.f, 0.f, 0.f);
    if (ltok >= 0) xv = *(const float4*)(X + (size_t)ltok * DM + k0 + lk4);
    XsT[lk4 + 0][lrow] = xv.x;
    XsT[lk4 + 1][lrow] = xv.y;
    XsT[lk4 + 2][lrow] = xv.z;
    XsT[lk4 + 3][lrow] = xv.w;
    #pragma unroll
    for (int q = 0; q < 8; ++q) {
      int fi  = tid + q * 256;       // 0..2047 float4s of the 32x256 W tile
      int kk  = fi >> 6;
      int col = (fi & 63) << 2;
      *(float4*)&Ws[kk][col] =
          *(const float4*)(W + (size_t)(k0 + kk) * QKV_C + c0 + col);
    }
    __syncthreads();
    #pragma unroll 4
    for (int kk = 0; kk < BK; ++kk) {
      const float4 a  = *(const float4*)&XsT[kk][ty << 2];
      const float4 b0 = *(const float4*)&Ws[kk][tx << 3];
      const float4 b1 = *(const float4*)&Ws[kk][(tx << 3) + 4];
      const float av[4] = {a.x, a.y, a.z, a.w};
      const float bv[8] = {b0.x, b0.y, b0.z, b0.w, b1.x, b1.y, b1.z, b1.w};
      #pragma unroll
      for (int i = 0; i < 4; ++i)
        #pragma unroll
        for (int j = 0; j < 8; ++j) acc[i][j] = fmaf(av[i], bv[j], acc[i][j]);
    }
    __syncthreads();
  }
  #pragma unroll
  for (int i = 0; i < 4; ++i) {
    int r = (ty << 2) + i;
    if (r < rows) {
      int tok = sorted[start + r];
      float* dst      = qkv + (size_t)tok * QKV_C + c0 + (tx << 3);
      const float* bb = bqkv + lab * QKV_C + c0 + (tx << 3);
      float4 o0 = make_float4(acc[i][0] + bb[0], acc[i][1] + bb[1],
                              acc[i][2] + bb[2], acc[i][3] + bb[3]);
      float4 o1 = make_float4(acc[i][4] + bb[4], acc[i][5] + bb[5],
                              acc[i][6] + bb[6], acc[i][7] + bb[7]);
      *(float4*)dst       = o0;
      *(float4*)(dst + 4) = o1;
    }
  }
}

// ---------------- kernel 3: flash attention (fp32) ----------------
// block = (q-tile 64 rows, head, batch); 256 threads; BR=BC=64; 4x4 micro
__global__ __launch_bounds__(256) void attn_k(float* qkv) {
  int qt = blockIdx.x, h = blockIdx.y, b = blockIdx.z;
  __shared__ float Qs[64][68];
  __shared__ float Ks[64][68];
  __shared__ float VsT[64][68];  // [d][c]
  __shared__ float Ps[64][68];

  int tid = threadIdx.x;
  int tx = tid & 15;   // col group (S cols / O dh cols): 4*tx..4*tx+3
  int ty = tid >> 4;   // row group: 4*ty..4*ty+3

  size_t rowbase = (size_t)b * SEQ;
  size_t hoff = (size_t)h * DH;

  // load Q tile (q region offset 0)
  #pragma unroll
  for (int q = 0; q < 4; ++q) {
    int fi = tid + q * 256;
    int r = fi >> 4;
    int c = (fi & 15) << 2;
    float4 v = *(const float4*)(qkv + (rowbase + qt * 64 + r) * QKV_C + hoff + c);
    Qs[r][c] = v.x; Qs[r][c + 1] = v.y; Qs[r][c + 2] = v.z; Qs[r][c + 3] = v.w;
  }

  float m_i[4], l_i[4], O[4][4];
  #pragma unroll
  for (int i = 0; i < 4; ++i) {
    m_i[i] = -1e30f; l_i[i] = 0.f;
    #pragma unroll
    for (int j = 0; j < 4; ++j) O[i][j] = 0.f;
  }

  for (int kt = 0; kt < SEQ / 64; ++kt) {
    #pragma unroll
    for (int q = 0; q < 4; ++q) {
      int fi = tid + q * 256;
      int r = fi >> 4;
      int c = (fi & 15) << 2;
      const float* src = qkv + (rowbase + kt * 64 + r) * QKV_C + hoff;
      float4 kv = *(const float4*)(src + DP + c);
      Ks[r][c] = kv.x; Ks[r][c + 1] = kv.y; Ks[r][c + 2] = kv.z; Ks[r][c + 3] = kv.w;
      float4 vv = *(const float4*)(src + 2 * DP + c);
      VsT[c + 0][r] = vv.x; VsT[c + 1][r] = vv.y; VsT[c + 2][r] = vv.z; VsT[c + 3][r] = vv.w;
    }
    __syncthreads();

    // S = Q K^T (4x4 per thread)
    float s[4][4];
    #pragma unroll
    for (int i = 0; i < 4; ++i)
      #pragma unroll
      for (int j = 0; j < 4; ++j) s[i][j] = 0.f;
    #pragma unroll 2
    for (int d4 = 0; d4 < DH; d4 += 4) {
      float4 a[4], bb[4];
      #pragma unroll
      for (int i = 0; i < 4; ++i) a[i] = *(const float4*)&Qs[(ty << 2) + i][d4];
      #pragma unroll
      for (int j = 0; j < 4; ++j) bb[j] = *(const float4*)&Ks[(tx << 2) + j][d4];
      #pragma unroll
      for (int i = 0; i < 4; ++i)
        #pragma unroll
        for (int j = 0; j < 4; ++j) {
          s[i][j] = fmaf(a[i].x, bb[j].x, s[i][j]);
          s[i][j] = fmaf(a[i].y, bb[j].y, s[i][j]);
          s[i][j] = fmaf(a[i].z, bb[j].z, s[i][j]);
          s[i][j] = fmaf(a[i].w, bb[j].w, s[i][j]);
        }
    }

    // online softmax (rows owned by 16-lane groups)
    #pragma unroll
    for (int i = 0; i < 4; ++i) {
      #pragma unroll
      for (int j = 0; j < 4; ++j) s[i][j] *= 0.125f;
      float mx = fmaxf(fmaxf(s[i][0], s[i][1]), fmaxf(s[i][2], s[i][3]));
      #pragma unroll
      for (int o = 1; o < 16; o <<= 1) mx = fmaxf(mx, __shfl_xor(mx, o, 16));
      float mnew = fmaxf(m_i[i], mx);
      float alpha = __expf(m_i[i] - mnew);
      float rsum = 0.f;
      #pragma unroll
      for (int j = 0; j < 4; ++j) { s[i][j] = __expf(s[i][j] - mnew); rsum += s[i][j]; }
      #pragma unroll
      for (int o = 1; o < 16; o <<= 1) rsum += __shfl_xor(rsum, o, 16);
      l_i[i] = l_i[i] * alpha + rsum;
      m_i[i] = mnew;
      #pragma unroll
      for (int j = 0; j < 4; ++j) O[i][j] *= alpha;
      *(float4*)&Ps[(ty << 2) + i][tx << 2] = make_float4(s[i][0], s[i][1], s[i][2], s[i][3]);
    }
    __syncthreads();

    // O += P V
    #pragma unroll 2
    for (int c4 = 0; c4 < 64; c4 += 4) {
      float4 p4[4], v4[4];
      #pragma unroll
      for (int i = 0; i < 4; ++i) p4[i] = *(const float4*)&Ps[(ty << 2) + i][c4];
      #pragma unroll
      for (int j = 0; j < 4; ++j) v4[j] = *(const float4*)&VsT[(tx << 2) + j][c4];
      #pragma unroll
      for (int i = 0; i < 4; ++i)
        #pragma unroll
        for (int j = 0; j < 4; ++j) {
          O[i][j] = fmaf(p4[i].x, v4[j].x, O[i][j]);
          O[i][j] = fmaf(p4[i].y, v4[j].y, O[i][j]);
          O[i][j] = fmaf(p4[i].z, v4[j].z, O[i][j]);
          O[i][j] = fmaf(p4[i].w, v4[j].w, O[i][j]);
        }
    }
    __syncthreads();
  }

  // write O into the q region (block-disjoint, safe in-place)
  #pragma unroll
  for (int i = 0; i < 4; ++i) {
    float inv = 1.f / l_i[i];
    int r = qt * 64 + (ty << 2) + i;
    float4 o = make_float4(O[i][0] * inv, O[i][1] * inv, O[i][2] * inv, O[i][3] * inv);
    *(float4*)(qkv + (rowbase + r) * QKV_C + hoff + (tx << 2)) = o;
  }
}

// ---------------- kernel 4: output projection GEMM ----------------
__global__ __launch_bounds__(256) void proj_gemm_k(
    const float* __restrict__ A, const float* __restrict__ W,
    const float* __restrict__ bias, float* __restrict__ out) {
  int t0 = blockIdx.y * TM;
  int c0 = blockIdx.x * TN;

  __shared__ float XsT[BK][TM + 4];
  __shared__ float Ws[BK][TN];

  int tid = threadIdx.x;
  int tx = tid & 31;
  int ty = tid >> 5;
  int lrow = tid >> 3;
  int lk4  = (tid & 7) << 2;

  float acc[4][8];
  #pragma unroll
  for (int i = 0; i < 4; ++i)
    #pragma unroll
    for (int j = 0; j < 8; ++j) acc[i][j] = 0.f;

  for (int k0 = 0; k0 < DP; k0 += BK) {
    float4 xv = *(const float4*)(A + (size_t)(t0 + lrow) * QKV_C + k0 + lk4);
    XsT[lk4 + 0][lrow] = xv.x;
    XsT[lk4 + 1][lrow] = xv.y;
    XsT[lk4 + 2][lrow] = xv.z;
    XsT[lk4 + 3][lrow] = xv.w;
    #pragma unroll
    for (int q = 0; q < 8; ++q) {
      int fi  = tid + q * 256;
      int kk  = fi >> 6;
      int col = (fi & 63) << 2;
      *(float4*)&Ws[kk][col] =
          *(const float4*)(W + (size_t)(k0 + kk) * DM + c0 + col);
    }
    __syncthreads();
    #pragma unroll 4
    for (int kk = 0; kk < BK; ++kk) {
      const float4 a  = *(const float4*)&XsT[kk][ty << 2];
      const float4 b0 = *(const float4*)&Ws[kk][tx << 3];
      const float4 b1 = *(const float4*)&Ws[kk][(tx << 3) + 4];
      const float av[4] = {a.x, a.y, a.z, a.w};
      const float bv[8] = {b0.x, b0.y, b0.z, b0.w, b1.x, b1.y, b1.z, b1.w};
      #pragma unroll
      for (int i = 0; i < 4; ++i)
        #pragma unroll
        for (int j = 0; j < 8; ++j) acc[i][j] = fmaf(av[i], bv[j], acc[i][j]);
    }
    __syncthreads();
  }
  #pragma unroll
  for (int i = 0; i < 4; ++i) {
    int r = t0 + (ty << 2) + i;
    float* dst      = out + (size_t)r * DM + c0 + (tx << 3);
    const float* bb = bias + c0 + (tx << 3);
    float4 o0 = make_float4(acc[i][0] + bb[0], acc[i][1] + bb[1],
                            acc[i][2] + bb[2], acc[i][3] + bb[3]);
    float4 o1 = make_float4(acc[i][4] + bb[4], acc[i][5] + bb[5],
                            acc[i][6] + bb[6], acc[i][7] + bb[7]);
    *(float4*)dst       = o0;
    *(float4*)(dst + 4) = o1;
  }
}

// ---------------- launch ----------------
extern "C" void kernel_launch(void* const* d_in, const int* in_sizes, int n_in,
                              void* d_out, int out_size, void* d_ws, size_t ws_size,
                              hipStream_t stream) {
  (void)in_sizes; (void)n_in; (void)out_size; (void)ws_size;
  const float* X     = (const float*)d_in[0];
  const int*   L     = (const int*)d_in[1];
  const float* Wqkv  = (const float*)d_in[2];
  const float* bqkv  = (const float*)d_in[3];
  const float* Wproj = (const float*)d_in[4];
  const float* bproj = (const float*)d_in[5];
  float* out = (float*)d_out;

  float* qkv  = (float*)d_ws;                                    // 8192 x 3072 f32
  int* sorted = (int*)((char*)d_ws + (size_t)TOK * QKV_C * sizeof(float));
  int* desc   = sorted + TOK;
  int* numt   = desc + 512;

  build_lists_k<<<dim3(1), dim3(256), 0, stream>>>(L, sorted, desc, numt);
  qkv_gemm_k<<<dim3(QKV_C / TN, 288), dim3(256), 0, stream>>>(
      X, Wqkv, bqkv, sorted, desc, numt, qkv);
  attn_k<<<dim3(SEQ / 64, NH, BATCH), dim3(256), 0, stream>>>(qkv);
  proj_gemm_k<<<dim3(DM / TN, TOK / TM), dim3(256), 0, stream>>>(
      qkv, Wproj, bproj, out);
}

// Round 2
// 2251.158 us; speedup vs baseline: 1.1132x; 1.1132x over previous
//
#include <hip/hip_runtime.h>
#include <math.h>

#define BATCH 4
#define SEQ   2048
#define TOK   (BATCH * SEQ)   // 8192
#define DM    1024
#define DP    1024
#define NH    16
#define DH    64
#define NLAB  8
#define QKV_C 3072

// ---------------- kernel 1: bucket tokens by label ----------------
__global__ void build_lists_k(const int* __restrict__ L, int* __restrict__ sorted,
                              int* __restrict__ desc, int* __restrict__ numt) {
  __shared__ int cnt[NLAB], off[NLAB], cur[NLAB];
  int tid = threadIdx.x;
  if (tid < NLAB) cnt[tid] = 0;
  __syncthreads();
  for (int i = tid; i < TOK; i += blockDim.x) atomicAdd(&cnt[L[i]], 1);
  __syncthreads();
  if (tid == 0) {
    int o = 0;
    for (int l = 0; l < NLAB; ++l) { off[l] = o; cur[l] = o; o += cnt[l]; }
  }
  __syncthreads();
  for (int i = tid; i < TOK; i += blockDim.x) {
    int l = L[i];
    int p = atomicAdd(&cur[l], 1);
    sorted[p] = i;
  }
  if (tid == 0) {
    int nt = 0;
    for (int l = 0; l < NLAB; ++l) {
      int c = cnt[l], o = off[l];
      for (int t = 0; t < c; t += 32) {
        int rows = c - t; if (rows > 32) rows = 32;
        desc[nt++] = (o + t) | (l << 16) | (rows << 20);
      }
    }
    *numt = nt;
  }
}

// ---------------- kernel 2: label-routed QKV GEMM ----------------
#define TM 32
#define TN 256
#define BK 32

__global__ __launch_bounds__(256) void qkv_gemm_k(
    const float* __restrict__ X, const float* __restrict__ Wqkv,
    const float* __restrict__ bqkv, const int* __restrict__ sorted,
    const int* __restrict__ desc, const int* __restrict__ numt,
    float* __restrict__ qkv) {
  int tile = blockIdx.y;
  if (tile >= *numt) return;
  int dsc   = desc[tile];
  int start = dsc & 0xFFFF;
  int lab   = (dsc >> 16) & 7;
  int rows  = (dsc >> 20) & 63;
  int c0    = blockIdx.x * TN;
  const float* W = Wqkv + (size_t)lab * DM * QKV_C;

  __shared__ float XsT[BK][TM + 4];
  __shared__ float Ws[BK][TN];

  int tid = threadIdx.x;
  int tx = tid & 31;
  int ty = tid >> 5;

  int lrow = tid >> 3;
  int lk4  = (tid & 7) << 2;
  int ltok = (lrow < rows) ? sorted[start + lrow] : -1;

  float acc[4][8];
  #pragma unroll
  for (int i = 0; i < 4; ++i)
    #pragma unroll
    for (int j = 0; j < 8; ++j) acc[i][j] = 0.f;

  for (int k0 = 0; k0 < DM; k0 += BK) {
    float4 xv = make_float4(0.f, 0.f, 0.f, 0.f);
    if (ltok >= 0) xv = *(const float4*)(X + (size_t)ltok * DM + k0 + lk4);
    XsT[lk4 + 0][lrow] = xv.x;
    XsT[lk4 + 1][lrow] = xv.y;
    XsT[lk4 + 2][lrow] = xv.z;
    XsT[lk4 + 3][lrow] = xv.w;
    #pragma unroll
    for (int q = 0; q < 8; ++q) {
      int fi  = tid + q * 256;
      int kk  = fi >> 6;
      int col = (fi & 63) << 2;
      *(float4*)&Ws[kk][col] =
          *(const float4*)(W + (size_t)(k0 + kk) * QKV_C + c0 + col);
    }
    __syncthreads();
    #pragma unroll 4
    for (int kk = 0; kk < BK; ++kk) {
      const float4 a  = *(const float4*)&XsT[kk][ty << 2];
      const float4 b0 = *(const float4*)&Ws[kk][tx << 3];
      const float4 b1 = *(const float4*)&Ws[kk][(tx << 3) + 4];
      const float av[4] = {a.x, a.y, a.z, a.w};
      const float bv[8] = {b0.x, b0.y, b0.z, b0.w, b1.x, b1.y, b1.z, b1.w};
      #pragma unroll
      for (int i = 0; i < 4; ++i)
        #pragma unroll
        for (int j = 0; j < 8; ++j) acc[i][j] = fmaf(av[i], bv[j], acc[i][j]);
    }
    __syncthreads();
  }
  #pragma unroll
  for (int i = 0; i < 4; ++i) {
    int r = (ty << 2) + i;
    if (r < rows) {
      int tok = sorted[start + r];
      float* dst      = qkv + (size_t)tok * QKV_C + c0 + (tx << 3);
      const float* bb = bqkv + lab * QKV_C + c0 + (tx << 3);
      float4 o0 = make_float4(acc[i][0] + bb[0], acc[i][1] + bb[1],
                              acc[i][2] + bb[2], acc[i][3] + bb[3]);
      float4 o1 = make_float4(acc[i][4] + bb[4], acc[i][5] + bb[5],
                              acc[i][6] + bb[6], acc[i][7] + bb[7]);
      *(float4*)dst       = o0;
      *(float4*)(dst + 4) = o1;
    }
  }
}

// ---------------- kernel 3: flash attention (fp32, conflict-free) ----------
// block = (q-tile 64 rows, head, batch); 256 threads; BR=BC=64; 4x4 micro.
// S-columns per lane: tx + 16*j  (consecutive-row K reads -> 2-way, free)
// dh-columns per lane: 4*tx..4*tx+3 (contiguous O stores)
// V stored XOR-swizzled: row r, col-block m lives at 68*r + 4*(m ^ (r&15)),
//   making BOTH the staging write and the PV transposed-read conflict-free.
// P aliases the K buffer (K dead after S) -> LDS 52.2KB -> 3 blocks/CU.
__global__ __launch_bounds__(256, 3) void attn_k(float* qkv) {
  int qt = blockIdx.x, h = blockIdx.y, b = blockIdx.z;
  __shared__ float Qs[64][68];
  __shared__ float KPs[64][68];   // K tile; reused as P after S-compute
  __shared__ float Vsw[64 * 68];  // V tile, XOR-swizzled

  int tid = threadIdx.x;
  int tx = tid & 15;
  int ty = tid >> 4;

  size_t rowbase = (size_t)b * SEQ;
  size_t hoff = (size_t)h * DH;

  // load Q tile (contiguous rows -> conflict-free b128 writes)
  #pragma unroll
  for (int q = 0; q < 4; ++q) {
    int fi = tid + q * 256;
    int r = fi >> 4;
    int c = (fi & 15) << 2;
    *(float4*)&Qs[r][c] =
        *(const float4*)(qkv + (rowbase + qt * 64 + r) * QKV_C + hoff + c);
  }

  float m_i[4], l_i[4], O[4][4];
  #pragma unroll
  for (int i = 0; i < 4; ++i) {
    m_i[i] = -1e30f; l_i[i] = 0.f;
    #pragma unroll
    for (int e = 0; e < 4; ++e) O[i][e] = 0.f;
  }

  // register prefetch of the K/V tile (consumed at loop top)
  float4 kreg[4], vreg[4];
  {
    #pragma unroll
    for (int q = 0; q < 4; ++q) {
      int fi = tid + q * 256;
      int r = fi >> 4;
      int c = (fi & 15) << 2;
      const float* src = qkv + (rowbase + r) * QKV_C + hoff;
      kreg[q] = *(const float4*)(src + DP + c);
      vreg[q] = *(const float4*)(src + 2 * DP + c);
    }
  }

  for (int kt = 0; kt < SEQ / 64; ++kt) {
    // commit prefetched tile to LDS
    #pragma unroll
    for (int q = 0; q < 4; ++q) {
      int fi = tid + q * 256;
      int r = fi >> 4;
      int m = fi & 15;
      *(float4*)&KPs[r][m << 2] = kreg[q];
      *(float4*)&Vsw[r * 68 + ((m ^ (r & 15)) << 2)] = vreg[q];
    }
    __syncthreads();

    // prefetch next tile into registers (hidden behind S+softmax+PV)
    if (kt + 1 < SEQ / 64) {
      #pragma unroll
      for (int q = 0; q < 4; ++q) {
        int fi = tid + q * 256;
        int r = fi >> 4;
        int c = (fi & 15) << 2;
        const float* src = qkv + (rowbase + (kt + 1) * 64 + r) * QKV_C + hoff;
        kreg[q] = *(const float4*)(src + DP + c);
        vreg[q] = *(const float4*)(src + 2 * DP + c);
      }
    }

    // S = Q K^T : per-lane rows 4ty..4ty+3, cols tx+16j
    float s[4][4];
    #pragma unroll
    for (int i = 0; i < 4; ++i)
      #pragma unroll
      for (int j = 0; j < 4; ++j) s[i][j] = 0.f;
    #pragma unroll 2
    for (int d4 = 0; d4 < DH; d4 += 4) {
      float4 a[4], kk[4];
      #pragma unroll
      for (int i = 0; i < 4; ++i) a[i] = *(const float4*)&Qs[(ty << 2) + i][d4];
      #pragma unroll
      for (int j = 0; j < 4; ++j) kk[j] = *(const float4*)&KPs[tx + 16 * j][d4];
      #pragma unroll
      for (int i = 0; i < 4; ++i)
        #pragma unroll
        for (int j = 0; j < 4; ++j) {
          s[i][j] = fmaf(a[i].x, kk[j].x, s[i][j]);
          s[i][j] = fmaf(a[i].y, kk[j].y, s[i][j]);
          s[i][j] = fmaf(a[i].z, kk[j].z, s[i][j]);
          s[i][j] = fmaf(a[i].w, kk[j].w, s[i][j]);
        }
    }
    __syncthreads();  // all K reads done before P overwrites the buffer

    // online softmax; write P into the K buffer
    #pragma unroll
    for (int i = 0; i < 4; ++i) {
      #pragma unroll
      for (int j = 0; j < 4; ++j) s[i][j] *= 0.125f;
      float mx = fmaxf(fmaxf(s[i][0], s[i][1]), fmaxf(s[i][2], s[i][3]));
      #pragma unroll
      for (int o = 1; o < 16; o <<= 1) mx = fmaxf(mx, __shfl_xor(mx, o, 16));
      float mnew = fmaxf(m_i[i], mx);
      float alpha = __expf(m_i[i] - mnew);
      float rsum = 0.f;
      #pragma unroll
      for (int j = 0; j < 4; ++j) { s[i][j] = __expf(s[i][j] - mnew); rsum += s[i][j]; }
      #pragma unroll
      for (int o = 1; o < 16; o <<= 1) rsum += __shfl_xor(rsum, o, 16);
      l_i[i] = l_i[i] * alpha + rsum;
      m_i[i] = mnew;
      #pragma unroll
      for (int e = 0; e < 4; ++e) O[i][e] *= alpha;
      #pragma unroll
      for (int j = 0; j < 4; ++j) KPs[(ty << 2) + i][tx + 16 * j] = s[i][j];
    }
    __syncthreads();  // P visible

    // O += P V : per-lane rows 4ty..4ty+3, dh cols 4tx..4tx+3
    #pragma unroll 2
    for (int c4 = 0; c4 < 64; c4 += 4) {
      float4 p[4], v[4];
      #pragma unroll
      for (int i = 0; i < 4; ++i) p[i] = *(const float4*)&KPs[(ty << 2) + i][c4];
      #pragma unroll
      for (int cc = 0; cc < 4; ++cc) {
        int r = c4 + cc;
        v[cc] = *(const float4*)&Vsw[r * 68 + ((tx ^ (r & 15)) << 2)];
      }
      #pragma unroll
      for (int i = 0; i < 4; ++i) {
        O[i][0] = fmaf(p[i].x, v[0].x, O[i][0]);
        O[i][1] = fmaf(p[i].x, v[0].y, O[i][1]);
        O[i][2] = fmaf(p[i].x, v[0].z, O[i][2]);
        O[i][3] = fmaf(p[i].x, v[0].w, O[i][3]);
        O[i][0] = fmaf(p[i].y, v[1].x, O[i][0]);
        O[i][1] = fmaf(p[i].y, v[1].y, O[i][1]);
        O[i][2] = fmaf(p[i].y, v[1].z, O[i][2]);
        O[i][3] = fmaf(p[i].y, v[1].w, O[i][3]);
        O[i][0] = fmaf(p[i].z, v[2].x, O[i][0]);
        O[i][1] = fmaf(p[i].z, v[2].y, O[i][1]);
        O[i][2] = fmaf(p[i].z, v[2].z, O[i][2]);
        O[i][3] = fmaf(p[i].z, v[2].w, O[i][3]);
        O[i][0] = fmaf(p[i].w, v[3].x, O[i][0]);
        O[i][1] = fmaf(p[i].w, v[3].y, O[i][1]);
        O[i][2] = fmaf(p[i].w, v[3].z, O[i][2]);
        O[i][3] = fmaf(p[i].w, v[3].w, O[i][3]);
      }
    }
    __syncthreads();  // PV done before next staging overwrites KPs/Vsw
  }

  // write O into the q region (block-disjoint, safe in-place)
  #pragma unroll
  for (int i = 0; i < 4; ++i) {
    float inv = 1.f / l_i[i];
    int r = qt * 64 + (ty << 2) + i;
    float4 o = make_float4(O[i][0] * inv, O[i][1] * inv, O[i][2] * inv, O[i][3] * inv);
    *(float4*)(qkv + (rowbase + r) * QKV_C + hoff + (tx << 2)) = o;
  }
}

// ---------------- kernel 4: output projection GEMM ----------------
__global__ __launch_bounds__(256) void proj_gemm_k(
    const float* __restrict__ A, const float* __restrict__ W,
    const float* __restrict__ bias, float* __restrict__ out) {
  int t0 = blockIdx.y * TM;
  int c0 = blockIdx.x * TN;

  __shared__ float XsT[BK][TM + 4];
  __shared__ float Ws[BK][TN];

  int tid = threadIdx.x;
  int tx = tid & 31;
  int ty = tid >> 5;
  int lrow = tid >> 3;
  int lk4  = (tid & 7) << 2;

  float acc[4][8];
  #pragma unroll
  for (int i = 0; i < 4; ++i)
    #pragma unroll
    for (int j = 0; j < 8; ++j) acc[i][j] = 0.f;

  for (int k0 = 0; k0 < DP; k0 += BK) {
    float4 xv = *(const float4*)(A + (size_t)(t0 + lrow) * QKV_C + k0 + lk4);
    XsT[lk4 + 0][lrow] = xv.x;
    XsT[lk4 + 1][lrow] = xv.y;
    XsT[lk4 + 2][lrow] = xv.z;
    XsT[lk4 + 3][lrow] = xv.w;
    #pragma unroll
    for (int q = 0; q < 8; ++q) {
      int fi  = tid + q * 256;
      int kk  = fi >> 6;
      int col = (fi & 63) << 2;
      *(float4*)&Ws[kk][col] =
          *(const float4*)(W + (size_t)(k0 + kk) * DM + c0 + col);
    }
    __syncthreads();
    #pragma unroll 4
    for (int kk = 0; kk < BK; ++kk) {
      const float4 a  = *(const float4*)&XsT[kk][ty << 2];
      const float4 b0 = *(const float4*)&Ws[kk][tx << 3];
      const float4 b1 = *(const float4*)&Ws[kk][(tx << 3) + 4];
      const float av[4] = {a.x, a.y, a.z, a.w};
      const float bv[8] = {b0.x, b0.y, b0.z, b0.w, b1.x, b1.y, b1.z, b1.w};
      #pragma unroll
      for (int i = 0; i < 4; ++i)
        #pragma unroll
        for (int j = 0; j < 8; ++j) acc[i][j] = fmaf(av[i], bv[j], acc[i][j]);
    }
    __syncthreads();
  }
  #pragma unroll
  for (int i = 0; i < 4; ++i) {
    int r = t0 + (ty << 2) + i;
    float* dst      = out + (size_t)r * DM + c0 + (tx << 3);
    const float* bb = bias + c0 + (tx << 3);
    float4 o0 = make_float4(acc[i][0] + bb[0], acc[i][1] + bb[1],
                            acc[i][2] + bb[2], acc[i][3] + bb[3]);
    float4 o1 = make_float4(acc[i][4] + bb[4], acc[i][5] + bb[5],
                            acc[i][6] + bb[6], acc[i][7] + bb[7]);
    *(float4*)dst       = o0;
    *(float4*)(dst + 4) = o1;
  }
}

// ---------------- launch ----------------
extern "C" void kernel_launch(void* const* d_in, const int* in_sizes, int n_in,
                              void* d_out, int out_size, void* d_ws, size_t ws_size,
                              hipStream_t stream) {
  (void)in_sizes; (void)n_in; (void)out_size; (void)ws_size;
  const float* X     = (const float*)d_in[0];
  const int*   L     = (const int*)d_in[1];
  const float* Wqkv  = (const float*)d_in[2];
  const float* bqkv  = (const float*)d_in[3];
  const float* Wproj = (const float*)d_in[4];
  const float* bproj = (const float*)d_in[5];
  float* out = (float*)d_out;

  float* qkv  = (float*)d_ws;                                    // 8192 x 3072 f32
  int* sorted = (int*)((char*)d_ws + (size_t)TOK * QKV_C * sizeof(float));
  int* desc   = sorted + TOK;
  int* numt   = desc + 512;

  build_lists_k<<<dim3(1), dim3(256), 0, stream>>>(L, sorted, desc, numt);
  qkv_gemm_k<<<dim3(QKV_C / TN, 288), dim3(256), 0, stream>>>(
      X, Wqkv, bqkv, sorted, desc, numt, qkv);
  attn_k<<<dim3(SEQ / 64, NH, BATCH), dim3(256), 0, stream>>>(qkv);
  proj_gemm_k<<<dim3(DM / TN, TOK / TM), dim3(256), 0, stream>>>(
      qkv, Wproj, bproj, out);
}

// Round 3
// 1366.574 us; speedup vs baseline: 1.8337x; 1.6473x over previous
//
#include <hip/hip_runtime.h>
#include <math.h>

#define BATCH 4
#define SEQ   2048
#define TOK   (BATCH * SEQ)   // 8192
#define DM    1024
#define DP    1024
#define NH    16
#define DH    64
#define NLAB  8
#define QKV_C 3072

typedef __attribute__((ext_vector_type(8))) short bf16x8;
typedef __attribute__((ext_vector_type(4))) float f32x4;

__device__ __forceinline__ short f2bf(float f) {
  union { float f; unsigned u; } v; v.f = f;
  unsigned r = v.u + 0x7FFF + ((v.u >> 16) & 1);   // RNE
  return (short)(r >> 16);
}

// ---------------- kernel 1: bucket tokens by label ----------------
__global__ void build_lists_k(const int* __restrict__ L, int* __restrict__ sorted,
                              int* __restrict__ desc, int* __restrict__ numt) {
  __shared__ int cnt[NLAB], off[NLAB], cur[NLAB];
  int tid = threadIdx.x;
  if (tid < NLAB) cnt[tid] = 0;
  __syncthreads();
  for (int i = tid; i < TOK; i += blockDim.x) atomicAdd(&cnt[L[i]], 1);
  __syncthreads();
  if (tid == 0) {
    int o = 0;
    for (int l = 0; l < NLAB; ++l) { off[l] = o; cur[l] = o; o += cnt[l]; }
  }
  __syncthreads();
  for (int i = tid; i < TOK; i += blockDim.x) {
    int l = L[i];
    int p = atomicAdd(&cur[l], 1);
    sorted[p] = i;
  }
  if (tid == 0) {
    int nt = 0;
    for (int l = 0; l < NLAB; ++l) {
      int c = cnt[l], o = off[l];
      for (int t = 0; t < c; t += 32) {
        int rows = c - t; if (rows > 32) rows = 32;
        desc[nt++] = (o + t) | (l << 16) | (rows << 20);
      }
    }
    *numt = nt;
  }
}

// ---------------- kernel 2: label-routed QKV GEMM (fp32) ----------------
#define TM 32
#define TN 256
#define BK 32

__global__ __launch_bounds__(256) void qkv_gemm_k(
    const float* __restrict__ X, const float* __restrict__ Wqkv,
    const float* __restrict__ bqkv, const int* __restrict__ sorted,
    const int* __restrict__ desc, const int* __restrict__ numt,
    float* __restrict__ qkv) {
  int tile = blockIdx.y;
  if (tile >= *numt) return;
  int dsc   = desc[tile];
  int start = dsc & 0xFFFF;
  int lab   = (dsc >> 16) & 7;
  int rows  = (dsc >> 20) & 63;
  int c0    = blockIdx.x * TN;
  const float* W = Wqkv + (size_t)lab * DM * QKV_C;

  __shared__ float XsT[BK][TM + 4];
  __shared__ float Ws[BK][TN];

  int tid = threadIdx.x;
  int tx = tid & 31;
  int ty = tid >> 5;

  int lrow = tid >> 3;
  int lk4  = (tid & 7) << 2;
  int ltok = (lrow < rows) ? sorted[start + lrow] : -1;

  float acc[4][8];
  #pragma unroll
  for (int i = 0; i < 4; ++i)
    #pragma unroll
    for (int j = 0; j < 8; ++j) acc[i][j] = 0.f;

  for (int k0 = 0; k0 < DM; k0 += BK) {
    float4 xv = make_float4(0.f, 0.f, 0.f, 0.f);
    if (ltok >= 0) xv = *(const float4*)(X + (size_t)ltok * DM + k0 + lk4);
    XsT[lk4 + 0][lrow] = xv.x;
    XsT[lk4 + 1][lrow] = xv.y;
    XsT[lk4 + 2][lrow] = xv.z;
    XsT[lk4 + 3][lrow] = xv.w;
    #pragma unroll
    for (int q = 0; q < 8; ++q) {
      int fi  = tid + q * 256;
      int kk  = fi >> 6;
      int col = (fi & 63) << 2;
      *(float4*)&Ws[kk][col] =
          *(const float4*)(W + (size_t)(k0 + kk) * QKV_C + c0 + col);
    }
    __syncthreads();
    #pragma unroll 4
    for (int kk = 0; kk < BK; ++kk) {
      const float4 a  = *(const float4*)&XsT[kk][ty << 2];
      const float4 b0 = *(const float4*)&Ws[kk][tx << 3];
      const float4 b1 = *(const float4*)&Ws[kk][(tx << 3) + 4];
      const float av[4] = {a.x, a.y, a.z, a.w};
      const float bv[8] = {b0.x, b0.y, b0.z, b0.w, b1.x, b1.y, b1.z, b1.w};
      #pragma unroll
      for (int i = 0; i < 4; ++i)
        #pragma unroll
        for (int j = 0; j < 8; ++j) acc[i][j] = fmaf(av[i], bv[j], acc[i][j]);
    }
    __syncthreads();
  }
  #pragma unroll
  for (int i = 0; i < 4; ++i) {
    int r = (ty << 2) + i;
    if (r < rows) {
      int tok = sorted[start + r];
      float* dst      = qkv + (size_t)tok * QKV_C + c0 + (tx << 3);
      const float* bb = bqkv + lab * QKV_C + c0 + (tx << 3);
      float4 o0 = make_float4(acc[i][0] + bb[0], acc[i][1] + bb[1],
                              acc[i][2] + bb[2], acc[i][3] + bb[3]);
      float4 o1 = make_float4(acc[i][4] + bb[4], acc[i][5] + bb[5],
                              acc[i][6] + bb[6], acc[i][7] + bb[7]);
      *(float4*)dst       = o0;
      *(float4*)(dst + 4) = o1;
    }
  }
}

// ---------------- kernel 3: flash attention, bf16 MFMA ----------------
// block = (64 q-rows, head, batch); 256 thr = 4 waves; wave w: q-rows 16w..16w+15
// mfma_f32_16x16x32_bf16. Verified layouts:
//   A-frag: lane holds A[m=lane&15][k=quad*8+j]   (row-major, b128)
//   B-frag: lane holds B[k=quad*8+j][n=lane&15]   (= row-major of B^T)
//   C/D   : lane holds D[row=quad*4+reg][col=lane&15]
// QK^T: A=Q rows, B=K rows (K row-major IS B^T). PV: A=P rows, B=VT rows.
// All tiles bf16 in LDS, row pitch 72 (144B) -> every b128 pattern hits the
// 8-cycle floor (even bank-group coverage). P round-trips LDS (C->A layout).
#define PITCH 72
__global__ __launch_bounds__(256) void attn_k(float* qkv) {
  int qt = blockIdx.x, h = blockIdx.y, b = blockIdx.z;
  __shared__ short Qs[64 * PITCH];
  __shared__ short Ks[64 * PITCH];
  __shared__ short VT[64 * PITCH];   // VT[d][kv]
  __shared__ short Ps[64 * PITCH];

  int tid  = threadIdx.x;
  int lane = tid & 63;
  int w    = tid >> 6;
  int col  = lane & 15;
  int quad = lane >> 4;

  size_t rowbase = (size_t)b * SEQ;
  int hoff = h * DH;

  // ---- stage Q (once), pre-scaled by 1/8 ----
  {
    int r    = tid >> 2;
    int dseg = (tid & 3) << 4;
    const float* src = qkv + (rowbase + qt * 64 + r) * QKV_C + hoff + dseg;
    short tmp[16];
    #pragma unroll
    for (int q4 = 0; q4 < 4; ++q4) {
      float4 v = *(const float4*)(src + q4 * 4);
      tmp[q4 * 4 + 0] = f2bf(v.x * 0.125f);
      tmp[q4 * 4 + 1] = f2bf(v.y * 0.125f);
      tmp[q4 * 4 + 2] = f2bf(v.z * 0.125f);
      tmp[q4 * 4 + 3] = f2bf(v.w * 0.125f);
    }
    *(bf16x8*)&Qs[r * PITCH + dseg]     = *(bf16x8*)&tmp[0];
    *(bf16x8*)&Qs[r * PITCH + dseg + 8] = *(bf16x8*)&tmp[8];
  }

  float m_r[4], l_r[4];
  f32x4 o_acc[4];
  #pragma unroll
  for (int r = 0; r < 4; ++r) {
    m_r[r] = -1e30f; l_r[r] = 0.f;
    o_acc[r] = (f32x4){0.f, 0.f, 0.f, 0.f};
  }

  for (int kt = 0; kt < SEQ / 64; ++kt) {
    // ---- stage K tile (row-major bf16) ----
    {
      int r    = tid >> 2;
      int dseg = (tid & 3) << 4;
      const float* src = qkv + (rowbase + kt * 64 + r) * QKV_C + DP + hoff + dseg;
      short tmp[16];
      #pragma unroll
      for (int q4 = 0; q4 < 4; ++q4) {
        float4 v = *(const float4*)(src + q4 * 4);
        tmp[q4 * 4 + 0] = f2bf(v.x);
        tmp[q4 * 4 + 1] = f2bf(v.y);
        tmp[q4 * 4 + 2] = f2bf(v.z);
        tmp[q4 * 4 + 3] = f2bf(v.w);
      }
      *(bf16x8*)&Ks[r * PITCH + dseg]     = *(bf16x8*)&tmp[0];
      *(bf16x8*)&Ks[r * PITCH + dseg + 8] = *(bf16x8*)&tmp[8];
    }
    // ---- stage V transposed: VT[d][kv]; lane d = lane, wave w: kv 16w..16w+15
    {
      const float* src = qkv + (rowbase + kt * 64 + (w << 4)) * QKV_C + 2 * DP + hoff + lane;
      short tmp[16];
      #pragma unroll
      for (int i = 0; i < 16; ++i) tmp[i] = f2bf(src[(size_t)i * QKV_C]);
      *(bf16x8*)&VT[lane * PITCH + (w << 4)]     = *(bf16x8*)&tmp[0];
      *(bf16x8*)&VT[lane * PITCH + (w << 4) + 8] = *(bf16x8*)&tmp[8];
    }
    __syncthreads();

    // ---- S = Q K^T ----
    f32x4 s_acc[4];
    #pragma unroll
    for (int nj = 0; nj < 4; ++nj) s_acc[nj] = (f32x4){0.f, 0.f, 0.f, 0.f};
    #pragma unroll
    for (int ks = 0; ks < 2; ++ks) {
      bf16x8 aQ = *(bf16x8*)&Qs[((w << 4) + col) * PITCH + (quad << 3) + (ks << 5)];
      #pragma unroll
      for (int nj = 0; nj < 4; ++nj) {
        bf16x8 bK = *(bf16x8*)&Ks[((nj << 4) + col) * PITCH + (quad << 3) + (ks << 5)];
        s_acc[nj] = __builtin_amdgcn_mfma_f32_16x16x32_bf16(aQ, bK, s_acc[nj], 0, 0, 0);
      }
    }

    // ---- online softmax (lane owns rows quad*4+r of its wave band) ----
    #pragma unroll
    for (int r = 0; r < 4; ++r) {
      float mx = fmaxf(fmaxf(s_acc[0][r], s_acc[1][r]),
                       fmaxf(s_acc[2][r], s_acc[3][r]));
      #pragma unroll
      for (int o = 1; o < 16; o <<= 1) mx = fmaxf(mx, __shfl_xor(mx, o, 16));
      float mnew  = fmaxf(m_r[r], mx);
      float alpha = __expf(m_r[r] - mnew);
      float p0 = __expf(s_acc[0][r] - mnew);
      float p1 = __expf(s_acc[1][r] - mnew);
      float p2 = __expf(s_acc[2][r] - mnew);
      float p3 = __expf(s_acc[3][r] - mnew);
      float rs = p0 + p1 + p2 + p3;
      #pragma unroll
      for (int o = 1; o < 16; o <<= 1) rs += __shfl_xor(rs, o, 16);
      l_r[r] = l_r[r] * alpha + rs;
      m_r[r] = mnew;
      #pragma unroll
      for (int nd = 0; nd < 4; ++nd) o_acc[nd][r] *= alpha;
      int prow = ((w << 4) + (quad << 2) + r) * PITCH;
      Ps[prow + col]      = f2bf(p0);
      Ps[prow + 16 + col] = f2bf(p1);
      Ps[prow + 32 + col] = f2bf(p2);
      Ps[prow + 48 + col] = f2bf(p3);
    }
    __syncthreads();

    // ---- O += P V ----
    #pragma unroll
    for (int ks = 0; ks < 2; ++ks) {
      bf16x8 aP = *(bf16x8*)&Ps[((w << 4) + col) * PITCH + (quad << 3) + (ks << 5)];
      #pragma unroll
      for (int nd = 0; nd < 4; ++nd) {
        bf16x8 bV = *(bf16x8*)&VT[((nd << 4) + col) * PITCH + (quad << 3) + (ks << 5)];
        o_acc[nd] = __builtin_amdgcn_mfma_f32_16x16x32_bf16(aP, bV, o_acc[nd], 0, 0, 0);
      }
    }
    __syncthreads();   // PV done before next staging overwrites Ks/VT
  }

  // ---- epilogue: O/l into the q region (block-disjoint, in-place) ----
  #pragma unroll
  for (int r = 0; r < 4; ++r) {
    float inv = 1.f / l_r[r];
    size_t grow = (rowbase + qt * 64 + (w << 4) + (quad << 2) + r) * QKV_C + hoff;
    #pragma unroll
    for (int nd = 0; nd < 4; ++nd)
      qkv[grow + (nd << 4) + col] = o_acc[nd][r] * inv;
  }
}

// ---------------- kernel 4: output projection GEMM (fp32) ----------------
__global__ __launch_bounds__(256) void proj_gemm_k(
    const float* __restrict__ A, const float* __restrict__ W,
    const float* __restrict__ bias, float* __restrict__ out) {
  int t0 = blockIdx.y * TM;
  int c0 = blockIdx.x * TN;

  __shared__ float XsT[BK][TM + 4];
  __shared__ float Ws[BK][TN];

  int tid = threadIdx.x;
  int tx = tid & 31;
  int ty = tid >> 5;
  int lrow = tid >> 3;
  int lk4  = (tid & 7) << 2;

  float acc[4][8];
  #pragma unroll
  for (int i = 0; i < 4; ++i)
    #pragma unroll
    for (int j = 0; j < 8; ++j) acc[i][j] = 0.f;

  for (int k0 = 0; k0 < DP; k0 += BK) {
    float4 xv = *(const float4*)(A + (size_t)(t0 + lrow) * QKV_C + k0 + lk4);
    XsT[lk4 + 0][lrow] = xv.x;
    XsT[lk4 + 1][lrow] = xv.y;
    XsT[lk4 + 2][lrow] = xv.z;
    XsT[lk4 + 3][lrow] = xv.w;
    #pragma unroll
    for (int q = 0; q < 8; ++q) {
      int fi  = tid + q * 256;
      int kk  = fi >> 6;
      int col = (fi & 63) << 2;
      *(float4*)&Ws[kk][col] =
          *(const float4*)(W + (size_t)(k0 + kk) * DM + c0 + col);
    }
    __syncthreads();
    #pragma unroll 4
    for (int kk = 0; kk < BK; ++kk) {
      const float4 a  = *(const float4*)&XsT[kk][ty << 2];
      const float4 b0 = *(const float4*)&Ws[kk][tx << 3];
      const float4 b1 = *(const float4*)&Ws[kk][(tx << 3) + 4];
      const float av[4] = {a.x, a.y, a.z, a.w};
      const float bv[8] = {b0.x, b0.y, b0.z, b0.w, b1.x, b1.y, b1.z, b1.w};
      #pragma unroll
      for (int i = 0; i < 4; ++i)
        #pragma unroll
        for (int j = 0; j < 8; ++j) acc[i][j] = fmaf(av[i], bv[j], acc[i][j]);
    }
    __syncthreads();
  }
  #pragma unroll
  for (int i = 0; i < 4; ++i) {
    int r = t0 + (ty << 2) + i;
    float* dst      = out + (size_t)r * DM + c0 + (tx << 3);
    const float* bb = bias + c0 + (tx << 3);
    float4 o0 = make_float4(acc[i][0] + bb[0], acc[i][1] + bb[1],
                            acc[i][2] + bb[2], acc[i][3] + bb[3]);
    float4 o1 = make_float4(acc[i][4] + bb[4], acc[i][5] + bb[5],
                            acc[i][6] + bb[6], acc[i][7] + bb[7]);
    *(float4*)dst       = o0;
    *(float4*)(dst + 4) = o1;
  }
}

// ---------------- launch ----------------
extern "C" void kernel_launch(void* const* d_in, const int* in_sizes, int n_in,
                              void* d_out, int out_size, void* d_ws, size_t ws_size,
                              hipStream_t stream) {
  (void)in_sizes; (void)n_in; (void)out_size; (void)ws_size;
  const float* X     = (const float*)d_in[0];
  const int*   L     = (const int*)d_in[1];
  const float* Wqkv  = (const float*)d_in[2];
  const float* bqkv  = (const float*)d_in[3];
  const float* Wproj = (const float*)d_in[4];
  const float* bproj = (const float*)d_in[5];
  float* out = (float*)d_out;

  float* qkv  = (float*)d_ws;                                    // 8192 x 3072 f32
  int* sorted = (int*)((char*)d_ws + (size_t)TOK * QKV_C * sizeof(float));
  int* desc   = sorted + TOK;
  int* numt   = desc + 512;

  build_lists_k<<<dim3(1), dim3(256), 0, stream>>>(L, sorted, desc, numt);
  qkv_gemm_k<<<dim3(QKV_C / TN, 288), dim3(256), 0, stream>>>(
      X, Wqkv, bqkv, sorted, desc, numt, qkv);
  attn_k<<<dim3(SEQ / 64, NH, BATCH), dim3(256), 0, stream>>>(qkv);
  proj_gemm_k<<<dim3(DM / TN, TOK / TM), dim3(256), 0, stream>>>(
      qkv, Wproj, bproj, out);
}

// Round 4
// 655.014 us; speedup vs baseline: 3.8257x; 2.0863x over previous
//
#include <hip/hip_runtime.h>
#include <math.h>

#define BATCH 4
#define SEQ   2048
#define TOK   (BATCH * SEQ)   // 8192
#define DM    1024
#define DP    1024
#define NH    16
#define DH    64
#define NLAB  8
#define QKV_C 3072
#define PADL  1152            // padded rows per label (9 x 128)
#define PROWS (NLAB * PADL)   // 9216
#define GP    72              // LDS row pitch (bf16 elems) - verified conflict-free

typedef __attribute__((ext_vector_type(8))) short bf16x8;
typedef __attribute__((ext_vector_type(4))) float f32x4;

__device__ __forceinline__ short f2bf(float f) {
  union { float f; unsigned u; } v; v.f = f;
  unsigned r = v.u + 0x7FFF + ((v.u >> 16) & 1);   // RNE
  return (short)(r >> 16);
}

// ---------------- kernel 1: bucket tokens, build padded rowmap ----------------
__global__ void build_lists_k(const int* __restrict__ L, int* __restrict__ sorted,
                              int* __restrict__ rowmap) {
  __shared__ int cnt[NLAB], off[NLAB], cur[NLAB];
  int tid = threadIdx.x;
  if (tid < NLAB) cnt[tid] = 0;
  __syncthreads();
  for (int i = tid; i < TOK; i += 256) atomicAdd(&cnt[L[i]], 1);
  __syncthreads();
  if (tid == 0) {
    int o = 0;
    for (int l = 0; l < NLAB; ++l) { off[l] = o; cur[l] = o; o += cnt[l]; }
  }
  __syncthreads();
  for (int i = tid; i < TOK; i += 256) {
    int l = L[i];
    sorted[atomicAdd(&cur[l], 1)] = i;
  }
  __threadfence();
  __syncthreads();
  for (int p = tid; p < PROWS; p += 256) {
    int l = p / PADL, i = p - l * PADL;
    rowmap[p] = (i < cnt[l]) ? sorted[off[l] + i] : -1;
  }
}

// ---------------- kernel 2: fp32 -> bf16 transpose  [K][N] -> [N][K] ---------
// grid (N/64, K/64, nmat); LDS pitch-65 fp32 (2-way banks = free, b128-aligned
// reads along k after transpose-in-LDS).
__global__ __launch_bounds__(256) void wt_k(const float* __restrict__ src,
                                            short* __restrict__ dst,
                                            int K, int N) {
  __shared__ float Ts[64][65];   // [n][k]
  int m = blockIdx.z;
  src += (size_t)m * K * N;
  dst += (size_t)m * (size_t)N * K;
  int n0 = blockIdx.x * 64, k0 = blockIdx.y * 64;
  int tid = threadIdx.x;
  int r = tid >> 4;              // k within tile (16 rows/pass)
  int c = (tid & 15) << 2;       // n within tile
  #pragma unroll
  for (int it = 0; it < 4; ++it) {
    float4 v = *(const float4*)(src + (size_t)(k0 + r + it * 16) * N + n0 + c);
    Ts[c + 0][r + it * 16] = v.x;
    Ts[c + 1][r + it * 16] = v.y;
    Ts[c + 2][r + it * 16] = v.z;
    Ts[c + 3][r + it * 16] = v.w;
  }
  __syncthreads();
  int n = tid >> 2, ks = (tid & 3) << 4;
  short tmp[16];
  #pragma unroll
  for (int j = 0; j < 16; ++j) tmp[j] = f2bf(Ts[n][ks + j]);
  *(bf16x8*)(dst + (size_t)(n0 + n) * K + k0 + ks)     = *(bf16x8*)&tmp[0];
  *(bf16x8*)(dst + (size_t)(n0 + n) * K + k0 + ks + 8) = *(bf16x8*)&tmp[8];
}

// ---------------- kernel 3: label-routed QKV GEMM, bf16 MFMA ----------------
// tile 128(tokens) x 128(cols), BK=64; 4 waves in 2x2, each 64x64 via 4x4
// grid of 16x16x32 MFMA. A gathered from fp32 X via rowmap (convert in
// staging); B from pre-transposed bf16 W[label][n][k]. Epilogue scatters
// bf16 rows into qkvb, folding bias and the 1/8 q-scale.
__global__ __launch_bounds__(256) void qkv_mfma_k(
    const float* __restrict__ X, const short* __restrict__ Wt,
    const float* __restrict__ bqkv, const int* __restrict__ rowmap,
    short* __restrict__ qkvb) {
  __shared__ short As[128 * GP];
  __shared__ short Bs[128 * GP];
  int bx = blockIdx.x, by = blockIdx.y;
  int lab = by / 9;
  int pr0 = by * 128;
  int n0  = bx * 128;
  const short* W = Wt + (size_t)lab * QKV_C * DM;   // [3072][1024] bf16

  int tid  = threadIdx.x;
  int lane = tid & 63, w = tid >> 6;
  int wm = w >> 1, wn = w & 1;
  int col = lane & 15, quad = lane >> 4;

  int srow = tid >> 2;            // staging row 0..63 (+64 on 2nd rep)
  int scol = (tid & 3) << 4;      // staging col 0,16,32,48

  int tokA0 = rowmap[pr0 + srow];
  int tokA1 = rowmap[pr0 + 64 + srow];
  const float* xr0 = (tokA0 >= 0) ? (X + (size_t)tokA0 * DM) : nullptr;
  const float* xr1 = (tokA1 >= 0) ? (X + (size_t)tokA1 * DM) : nullptr;

  f32x4 acc[4][4];
  #pragma unroll
  for (int mi = 0; mi < 4; ++mi)
    #pragma unroll
    for (int ni = 0; ni < 4; ++ni) acc[mi][ni] = (f32x4){0.f, 0.f, 0.f, 0.f};

  for (int k0 = 0; k0 < DM; k0 += 64) {
    // ---- stage A (gather + convert) ----
    #pragma unroll
    for (int rep = 0; rep < 2; ++rep) {
      const float* xr = rep ? xr1 : xr0;
      int row = srow + rep * 64;
      short tmp[16];
      if (xr) {
        #pragma unroll
        for (int q4 = 0; q4 < 4; ++q4) {
          float4 v = *(const float4*)(xr + k0 + scol + q4 * 4);
          tmp[q4 * 4 + 0] = f2bf(v.x);
          tmp[q4 * 4 + 1] = f2bf(v.y);
          tmp[q4 * 4 + 2] = f2bf(v.z);
          tmp[q4 * 4 + 3] = f2bf(v.w);
        }
      } else {
        #pragma unroll
        for (int j = 0; j < 16; ++j) tmp[j] = 0;
      }
      *(bf16x8*)&As[row * GP + scol]     = *(bf16x8*)&tmp[0];
      *(bf16x8*)&As[row * GP + scol + 8] = *(bf16x8*)&tmp[8];
    }
    // ---- stage B (bf16 copy) ----
    #pragma unroll
    for (int rep = 0; rep < 2; ++rep) {
      int row = srow + rep * 64;
      const short* wsrc = W + (size_t)(n0 + row) * DM + k0 + scol;
      *(bf16x8*)&Bs[row * GP + scol]     = *(const bf16x8*)(wsrc);
      *(bf16x8*)&Bs[row * GP + scol + 8] = *(const bf16x8*)(wsrc + 8);
    }
    __syncthreads();
    #pragma unroll
    for (int ks = 0; ks < 2; ++ks) {
      bf16x8 a[4], b[4];
      #pragma unroll
      for (int mi = 0; mi < 4; ++mi)
        a[mi] = *(bf16x8*)&As[(wm * 64 + mi * 16 + col) * GP + ks * 32 + (quad << 3)];
      #pragma unroll
      for (int ni = 0; ni < 4; ++ni)
        b[ni] = *(bf16x8*)&Bs[(wn * 64 + ni * 16 + col) * GP + ks * 32 + (quad << 3)];
      #pragma unroll
      for (int mi = 0; mi < 4; ++mi)
        #pragma unroll
        for (int ni = 0; ni < 4; ++ni)
          acc[mi][ni] = __builtin_amdgcn_mfma_f32_16x16x32_bf16(a[mi], b[ni], acc[mi][ni], 0, 0, 0);
    }
    __syncthreads();
  }

  // ---- epilogue: +bias, q-scale, scatter rows, store bf16 ----
  float scale = (bx < 8) ? 0.125f : 1.0f;
  const float* bias = bqkv + lab * QKV_C;
  #pragma unroll
  for (int mi = 0; mi < 4; ++mi) {
    #pragma unroll
    for (int r = 0; r < 4; ++r) {
      int prow = pr0 + wm * 64 + mi * 16 + (quad << 2) + r;
      int t2 = rowmap[prow];
      if (t2 < 0) continue;
      #pragma unroll
      for (int ni = 0; ni < 4; ++ni) {
        int gn = n0 + wn * 64 + ni * 16 + col;
        float v = (acc[mi][ni][r] + bias[gn]) * scale;
        qkvb[(size_t)t2 * QKV_C + gn] = f2bf(v);
      }
    }
  }
}

// ---------------- kernel 4: flash attention, bf16 MFMA, bf16 I/O -----------
__global__ __launch_bounds__(256) void attn_k(short* qkvb) {
  int qt = blockIdx.x, h = blockIdx.y, b = blockIdx.z;
  __shared__ short Qs[64 * GP];
  __shared__ short Ks[64 * GP];
  __shared__ short VT[64 * GP];   // VT[d][kv]
  __shared__ short Ps[64 * GP];

  int tid  = threadIdx.x;
  int lane = tid & 63;
  int w    = tid >> 6;
  int col  = lane & 15;
  int quad = lane >> 4;

  size_t rowbase = (size_t)b * SEQ;
  int hoff = h * DH;

  // ---- stage Q (already 1/8-scaled in GEMM epilogue) ----
  {
    int r = tid >> 2, c = (tid & 3) << 4;
    const short* src = qkvb + (rowbase + qt * 64 + r) * QKV_C + hoff + c;
    *(bf16x8*)&Qs[r * GP + c]     = *(const bf16x8*)(src);
    *(bf16x8*)&Qs[r * GP + c + 8] = *(const bf16x8*)(src + 8);
  }

  float m_r[4], l_r[4];
  f32x4 o_acc[4];
  #pragma unroll
  for (int r = 0; r < 4; ++r) {
    m_r[r] = -1e30f; l_r[r] = 0.f;
    o_acc[r] = (f32x4){0.f, 0.f, 0.f, 0.f};
  }

  for (int kt = 0; kt < SEQ / 64; ++kt) {
    {
      int r = tid >> 2, c = (tid & 3) << 4;
      const short* src = qkvb + (rowbase + kt * 64 + r) * QKV_C + DP + hoff + c;
      *(bf16x8*)&Ks[r * GP + c]     = *(const bf16x8*)(src);
      *(bf16x8*)&Ks[r * GP + c + 8] = *(const bf16x8*)(src + 8);
    }
    {
      const short* src = qkvb + (rowbase + kt * 64 + (w << 4)) * QKV_C + 2 * DP + hoff + lane;
      short tmp[16];
      #pragma unroll
      for (int i = 0; i < 16; ++i) tmp[i] = src[(size_t)i * QKV_C];
      *(bf16x8*)&VT[lane * GP + (w << 4)]     = *(bf16x8*)&tmp[0];
      *(bf16x8*)&VT[lane * GP + (w << 4) + 8] = *(bf16x8*)&tmp[8];
    }
    __syncthreads();

    // ---- S = Q K^T ----
    f32x4 s_acc[4];
    #pragma unroll
    for (int nj = 0; nj < 4; ++nj) s_acc[nj] = (f32x4){0.f, 0.f, 0.f, 0.f};
    #pragma unroll
    for (int ks = 0; ks < 2; ++ks) {
      bf16x8 aQ = *(bf16x8*)&Qs[((w << 4) + col) * GP + (quad << 3) + (ks << 5)];
      #pragma unroll
      for (int nj = 0; nj < 4; ++nj) {
        bf16x8 bK = *(bf16x8*)&Ks[((nj << 4) + col) * GP + (quad << 3) + (ks << 5)];
        s_acc[nj] = __builtin_amdgcn_mfma_f32_16x16x32_bf16(aQ, bK, s_acc[nj], 0, 0, 0);
      }
    }

    // ---- online softmax ----
    #pragma unroll
    for (int r = 0; r < 4; ++r) {
      float mx = fmaxf(fmaxf(s_acc[0][r], s_acc[1][r]),
                       fmaxf(s_acc[2][r], s_acc[3][r]));
      #pragma unroll
      for (int o = 1; o < 16; o <<= 1) mx = fmaxf(mx, __shfl_xor(mx, o, 16));
      float mnew  = fmaxf(m_r[r], mx);
      float alpha = __expf(m_r[r] - mnew);
      float p0 = __expf(s_acc[0][r] - mnew);
      float p1 = __expf(s_acc[1][r] - mnew);
      float p2 = __expf(s_acc[2][r] - mnew);
      float p3 = __expf(s_acc[3][r] - mnew);
      float rs = p0 + p1 + p2 + p3;
      #pragma unroll
      for (int o = 1; o < 16; o <<= 1) rs += __shfl_xor(rs, o, 16);
      l_r[r] = l_r[r] * alpha + rs;
      m_r[r] = mnew;
      #pragma unroll
      for (int nd = 0; nd < 4; ++nd) o_acc[nd][r] *= alpha;
      int prow = ((w << 4) + (quad << 2) + r) * GP;
      Ps[prow + col]      = f2bf(p0);
      Ps[prow + 16 + col] = f2bf(p1);
      Ps[prow + 32 + col] = f2bf(p2);
      Ps[prow + 48 + col] = f2bf(p3);
    }
    __syncthreads();

    // ---- O += P V ----
    #pragma unroll
    for (int ks = 0; ks < 2; ++ks) {
      bf16x8 aP = *(bf16x8*)&Ps[((w << 4) + col) * GP + (quad << 3) + (ks << 5)];
      #pragma unroll
      for (int nd = 0; nd < 4; ++nd) {
        bf16x8 bV = *(bf16x8*)&VT[((nd << 4) + col) * GP + (quad << 3) + (ks << 5)];
        o_acc[nd] = __builtin_amdgcn_mfma_f32_16x16x32_bf16(aP, bV, o_acc[nd], 0, 0, 0);
      }
    }
    __syncthreads();
  }

  // ---- epilogue: O/l as bf16 into the q region (block-disjoint) ----
  #pragma unroll
  for (int r = 0; r < 4; ++r) {
    float inv = 1.f / l_r[r];
    size_t grow = (rowbase + qt * 64 + (w << 4) + (quad << 2) + r) * QKV_C + hoff;
    #pragma unroll
    for (int nd = 0; nd < 4; ++nd)
      qkvb[grow + (nd << 4) + col] = f2bf(o_acc[nd][r] * inv);
  }
}

// ---------------- kernel 5: output projection, bf16 MFMA ----------------
__global__ __launch_bounds__(256) void proj_mfma_k(
    const short* __restrict__ Ab, const short* __restrict__ Wt,
    const float* __restrict__ bias, float* __restrict__ out) {
  __shared__ short As[128 * GP];
  __shared__ short Bs[128 * GP];
  int n0 = blockIdx.x * 128, m0 = blockIdx.y * 128;

  int tid  = threadIdx.x;
  int lane = tid & 63, w = tid >> 6;
  int wm = w >> 1, wn = w & 1;
  int col = lane & 15, quad = lane >> 4;
  int srow = tid >> 2;
  int scol = (tid & 3) << 4;

  f32x4 acc[4][4];
  #pragma unroll
  for (int mi = 0; mi < 4; ++mi)
    #pragma unroll
    for (int ni = 0; ni < 4; ++ni) acc[mi][ni] = (f32x4){0.f, 0.f, 0.f, 0.f};

  for (int k0 = 0; k0 < DP; k0 += 64) {
    #pragma unroll
    for (int rep = 0; rep < 2; ++rep) {
      int row = srow + rep * 64;
      const short* asrc = Ab + (size_t)(m0 + row) * QKV_C + k0 + scol;
      *(bf16x8*)&As[row * GP + scol]     = *(const bf16x8*)(asrc);
      *(bf16x8*)&As[row * GP + scol + 8] = *(const bf16x8*)(asrc + 8);
      const short* wsrc = Wt + (size_t)(n0 + row) * DP + k0 + scol;
      *(bf16x8*)&Bs[row * GP + scol]     = *(const bf16x8*)(wsrc);
      *(bf16x8*)&Bs[row * GP + scol + 8] = *(const bf16x8*)(wsrc + 8);
    }
    __syncthreads();
    #pragma unroll
    for (int ks = 0; ks < 2; ++ks) {
      bf16x8 a[4], b[4];
      #pragma unroll
      for (int mi = 0; mi < 4; ++mi)
        a[mi] = *(bf16x8*)&As[(wm * 64 + mi * 16 + col) * GP + ks * 32 + (quad << 3)];
      #pragma unroll
      for (int ni = 0; ni < 4; ++ni)
        b[ni] = *(bf16x8*)&Bs[(wn * 64 + ni * 16 + col) * GP + ks * 32 + (quad << 3)];
      #pragma unroll
      for (int mi = 0; mi < 4; ++mi)
        #pragma unroll
        for (int ni = 0; ni < 4; ++ni)
          acc[mi][ni] = __builtin_amdgcn_mfma_f32_16x16x32_bf16(a[mi], b[ni], acc[mi][ni], 0, 0, 0);
    }
    __syncthreads();
  }

  #pragma unroll
  for (int mi = 0; mi < 4; ++mi) {
    #pragma unroll
    for (int r = 0; r < 4; ++r) {
      int m = m0 + wm * 64 + mi * 16 + (quad << 2) + r;
      #pragma unroll
      for (int ni = 0; ni < 4; ++ni) {
        int gn = n0 + wn * 64 + ni * 16 + col;
        out[(size_t)m * DM + gn] = acc[mi][ni][r] + bias[gn];
      }
    }
  }
}

// ---------------- launch ----------------
extern "C" void kernel_launch(void* const* d_in, const int* in_sizes, int n_in,
                              void* d_out, int out_size, void* d_ws, size_t ws_size,
                              hipStream_t stream) {
  (void)in_sizes; (void)n_in; (void)out_size; (void)ws_size;
  const float* X     = (const float*)d_in[0];
  const int*   L     = (const int*)d_in[1];
  const float* Wqkv  = (const float*)d_in[2];
  const float* bqkv  = (const float*)d_in[3];
  const float* Wproj = (const float*)d_in[4];
  const float* bproj = (const float*)d_in[5];
  float* out = (float*)d_out;

  char* ws = (char*)d_ws;
  short* qkvb    = (short*)ws;                                   // 8192x3072 bf16 (50.3 MB)
  short* Wqkv_t  = (short*)(ws + (size_t)TOK * QKV_C * 2);       // 8x3072x1024 bf16 (50.3 MB)
  short* Wproj_t = (short*)(ws + (size_t)TOK * QKV_C * 2
                               + (size_t)NLAB * QKV_C * DM * 2); // 1024x1024 bf16 (2.1 MB)
  int* sorted = (int*)((char*)Wproj_t + (size_t)DP * DM * 2);
  int* rowmap = sorted + TOK;

  build_lists_k<<<dim3(1), dim3(256), 0, stream>>>(L, sorted, rowmap);
  wt_k<<<dim3(QKV_C / 64, DM / 64, NLAB), dim3(256), 0, stream>>>(Wqkv, Wqkv_t, DM, QKV_C);
  wt_k<<<dim3(DM / 64, DP / 64, 1), dim3(256), 0, stream>>>(Wproj, Wproj_t, DP, DM);
  qkv_mfma_k<<<dim3(QKV_C / 128, PROWS / 128), dim3(256), 0, stream>>>(
      X, Wqkv_t, bqkv, rowmap, qkvb);
  attn_k<<<dim3(SEQ / 64, NH, BATCH), dim3(256), 0, stream>>>(qkvb);
  proj_mfma_k<<<dim3(DM / 128, TOK / 128), dim3(256), 0, stream>>>(
      qkvb, Wproj_t, bproj, out);
}